// Round 3
// baseline (640.877 us; speedup 1.0000x reference)
//
#include <hip/hip_runtime.h>

#define NB 4
#define NN 65536
#define NK 16
#define NP (NB * NN)   // 262144 points
#define BN_EPS 1e-6f

// ---- workspace layout (floats) ----
// raw sums (zeroed each launch):
// enc moments over all (p,k), basis [cx,cy,cz,nx,ny,nz,1]:
//   [0..2] S_c(x16/pt)  [3..5] S_n  [6..11] M_cc upper  [12..20] M_cn 3x3  [21..26] M_nn upper
#define WS_ENC_M   0    // 27 floats
#define WS_SC_M    32   // S_f[8] @32, M_ff upper-tri 36 @40  (44 floats)
#define WS_S_Y2    96   // 8  pool1 conv sum
#define WS_SS_Y2   104  // 8
#define WS_S_Y4    112  // 16 pool2 conv sum
#define WS_SS_Y4   128  // 16 -> raw stats end at 144
// big buffers, channel-major [c][p] for coalesced access
#define WS_Y2      1024             // NP*8  floats (8 MB)
#define WS_Y4      (1024 + NP * 8)  // NP*16 floats (16 MB)
// coords as float4 live in d_out[0 .. NP*4) — k_final overwrites d_out last.

template <int NCH>
__device__ inline void blockReduceAtomic(float (&v)[NCH], float* __restrict__ dst) {
    __shared__ float red[4][NCH];
    const int lane = threadIdx.x & 63;
    const int wv = threadIdx.x >> 6;
#pragma unroll
    for (int c = 0; c < NCH; c++) {
        float x = v[c];
#pragma unroll
        for (int off = 32; off > 0; off >>= 1) x += __shfl_xor(x, off, 64);
        if (lane == 0) red[wv][c] = x;
    }
    __syncthreads();
    for (int c = threadIdx.x; c < NCH; c += 256)
        atomicAdd(dst + c, red[0][c] + red[1][c] + red[2][c] + red[3][c]);
}

// bn scale/shift for an lse conv channel from enc moments. w points at 10 weights.
__device__ inline void bn_from_enc(const float* __restrict__ M, const float* __restrict__ w,
                                   float b, float g, float bt, float& sc, float& sh) {
    float u[6];
    u[0] = w[0] + w[6]; u[1] = w[1] + w[7]; u[2] = w[2] + w[8];
    u[3] = w[3] - w[6]; u[4] = w[4] - w[7]; u[5] = w[5] - w[8];
    const float beta = b + w[9];
    float lin = 0.f;
#pragma unroll
    for (int i = 0; i < 6; i++) lin += u[i] * M[i];
    float quad = u[0] * u[0] * M[6] + 2.f * u[0] * u[1] * M[7] + 2.f * u[0] * u[2] * M[8]
               + u[1] * u[1] * M[9] + 2.f * u[1] * u[2] * M[10] + u[2] * u[2] * M[11];
#pragma unroll
    for (int i = 0; i < 3; i++)
#pragma unroll
        for (int j = 0; j < 3; j++) quad += 2.f * u[i] * u[3 + j] * M[12 + i * 3 + j];
    quad += u[3] * u[3] * M[21] + 2.f * u[3] * u[4] * M[22] + 2.f * u[3] * u[5] * M[23]
          + u[4] * u[4] * M[24] + 2.f * u[4] * u[5] * M[25] + u[5] * u[5] * M[26];
    const float cnt = (float)NP * (float)NK;
    const float sum = lin + cnt * beta;
    const float ss = quad + 2.f * beta * lin + cnt * beta * beta;
    const float m = sum / cnt, v = ss / cnt - m * m;
    sc = g * rsqrtf(v + BN_EPS);
    sh = bt - m * sc;
}

// ---------------- Kernel 1: pack coords -> float4 (in d_out scratch) + shortcut feat moments
__global__ __launch_bounds__(256) void k_prep(
    const float* __restrict__ coords, const float* __restrict__ feats,
    float4* __restrict__ c4, float* __restrict__ ws) {
    const int tid = threadIdx.x;
    const int p = blockIdx.x * 256 + tid;
    const int b = p >> 16;
    const int n = p & (NN - 1);
    c4[p] = make_float4(coords[3 * p], coords[3 * p + 1], coords[3 * p + 2], 0.f);
    float accf[44];
    float f[8];
#pragma unroll
    for (int i = 0; i < 8; i++) f[i] = feats[(b * 8 + i) * NN + n];
#pragma unroll
    for (int i = 0; i < 8; i++) accf[i] = f[i];
    int t2 = 8;
#pragma unroll
    for (int i = 0; i < 8; i++)
#pragma unroll
        for (int j = i; j < 8; j++) accf[t2++] = f[i] * f[j];
    blockReduceAtomic<44>(accf, ws + WS_SC_M);
}

// ---------------- Kernel 2: enc moments (float4 gathers)
__global__ __launch_bounds__(256) void k_stats(
    const float4* __restrict__ c4, const int* __restrict__ idx, float* __restrict__ ws) {
    const int tid = threadIdx.x;
    const int p = blockIdx.x * 256 + tid;
    const int boff = (p >> 16) << 16;
    const float4 me = c4[p];
    const int4* ip = (const int4*)idx + p * 4;
    float sn0 = 0.f, sn1 = 0.f, sn2 = 0.f;
    float m00 = 0.f, m01 = 0.f, m02 = 0.f, m11 = 0.f, m12 = 0.f, m22 = 0.f;
#pragma unroll
    for (int q = 0; q < 4; q++) {
        int4 v = ip[q];
        int jj[4] = {v.x, v.y, v.z, v.w};
#pragma unroll
        for (int e = 0; e < 4; e++) {
            const float4 nn = c4[boff + jj[e]];
            sn0 += nn.x; sn1 += nn.y; sn2 += nn.z;
            m00 += nn.x * nn.x; m01 += nn.x * nn.y; m02 += nn.x * nn.z;
            m11 += nn.y * nn.y; m12 += nn.y * nn.z; m22 += nn.z * nn.z;
        }
    }
    float acc[27];
    acc[0] = 16.f * me.x; acc[1] = 16.f * me.y; acc[2] = 16.f * me.z;
    acc[3] = sn0; acc[4] = sn1; acc[5] = sn2;
    acc[6] = 16.f * me.x * me.x; acc[7] = 16.f * me.x * me.y; acc[8] = 16.f * me.x * me.z;
    acc[9] = 16.f * me.y * me.y; acc[10] = 16.f * me.y * me.z; acc[11] = 16.f * me.z * me.z;
    acc[12] = me.x * sn0; acc[13] = me.x * sn1; acc[14] = me.x * sn2;
    acc[15] = me.y * sn0; acc[16] = me.y * sn1; acc[17] = me.y * sn2;
    acc[18] = me.z * sn0; acc[19] = me.z * sn1; acc[20] = me.z * sn2;
    acc[21] = m00; acc[22] = m01; acc[23] = m02;
    acc[24] = m11; acc[25] = m12; acc[26] = m22;
    blockReduceAtomic<27>(acc, ws + WS_ENC_M);
}

// ---------------- Kernel 3: mlp1 + lse1 + pool1 -> y2 (pre-BN), bn_p1 raw sums
__global__ __launch_bounds__(256, 4) void k_pool1(
    const float4* __restrict__ c4, const float* __restrict__ feats,
    const int* __restrict__ idx,
    const float* __restrict__ w1, const float* __restrict__ b1,
    const float* __restrict__ lse1_w, const float* __restrict__ lse1_b,
    const float* __restrict__ lse1_g, const float* __restrict__ lse1_bt,
    const float* __restrict__ p1_sw, const float* __restrict__ p1_w,
    const float* __restrict__ p1_b, float* __restrict__ ws) {
    // an: bn-folded neighbor weights; dc3/dcon: per-point affine precursor
    __shared__ float an[24], dc3[24], dcon[8], sws[64], pws[128], pbs[8], w1s[64], b1s[8];
    const int tid = threadIdx.x;
    if (tid < 8) {
        const int c = tid;
        const float* w = lse1_w + c * 10;
        float sc, sh;
        bn_from_enc(ws + WS_ENC_M, w, lse1_b[c], lse1_g[c], lse1_bt[c], sc, sh);
#pragma unroll
        for (int i = 0; i < 3; i++) {
            an[c * 3 + i] = sc * (w[3 + i] - w[6 + i]);
            dc3[c * 3 + i] = sc * (w[i] + w[6 + i]);
        }
        dcon[c] = sc * (lse1_b[c] + w[9]) + sh;
        b1s[c] = b1[c]; pbs[c] = p1_b[c];
    }
    if (tid < 64) {
        w1s[tid] = w1[tid];
        sws[tid] = p1_sw[(tid >> 3) * 16 + (tid & 7)];  // only 8x8 block matters
    }
    if (tid < 128) pws[tid] = p1_w[tid];
    __syncthreads();

    const int p = blockIdx.x * 256 + tid;
    const int b = p >> 16;
    const int n = p & (NN - 1);
    const int boff = b << 16;
    const float4 me = c4[p];
    float d[8];
#pragma unroll
    for (int c = 0; c < 8; c++)
        d[c] = dc3[c * 3] * me.x + dc3[c * 3 + 1] * me.y + dc3[c * 3 + 2] * me.z + dcon[c];
    const int4* ip = (const int4*)idx + p * 4;
    float l[8] = {}, ac[8] = {};
#pragma unroll
    for (int q = 0; q < 4; q++) {
        int4 v = ip[q];
        int jj[4] = {v.x, v.y, v.z, v.w};
#pragma unroll
        for (int e = 0; e < 4; e++) {
            const float4 nn = c4[boff + jj[e]];
            float h[8];
#pragma unroll
            for (int c = 0; c < 8; c++) {
                float y = an[c * 3] * nn.x + an[c * 3 + 1] * nn.y + an[c * 3 + 2] * nn.z + d[c];
                h[c] = y > 0.f ? y : 0.f;
            }
#pragma unroll
            for (int o = 0; o < 8; o++) {
                float s = 0.f;
#pragma unroll
                for (int i = 0; i < 8; i++) s += h[i] * sws[o * 8 + i];
                float e2 = __expf(s);  // k-constant part of score cancels in softmax
                l[o] += e2; ac[o] += e2 * h[o];
            }
        }
    }
    // epilogue: mlp1 (broadcast channels pool to themselves), pool1 conv
    float f[8];
#pragma unroll
    for (int i = 0; i < 8; i++) f[i] = feats[(b * 8 + i) * NN + n];
    float agg[16];
#pragma unroll
    for (int o = 0; o < 8; o++) agg[o] = ac[o] / l[o];
#pragma unroll
    for (int j = 0; j < 8; j++) {
        float y = b1s[j];
#pragma unroll
        for (int i = 0; i < 8; i++) y += f[i] * w1s[j * 8 + i];
        agg[8 + j] = y > 0.f ? y : 0.2f * y;  // LeakyReLU(0.2)
    }
    float st[16];
#pragma unroll
    for (int c = 0; c < 8; c++) {
        float y = pbs[c];
#pragma unroll
        for (int o = 0; o < 16; o++) y += agg[o] * pws[c * 16 + o];
        ws[WS_Y2 + c * NP + p] = y;
        st[c] = y; st[8 + c] = y * y;
    }
    blockReduceAtomic<16>(st, ws + WS_S_Y2);
}

// ---------------- Kernel 4: bn_p1+relu -> x2, lse2 + pool2 -> y4 (pre-BN), bn_p2 raw sums
__global__ __launch_bounds__(256, 4) void k_pool2(
    const float4* __restrict__ c4, const int* __restrict__ idx,
    const float* __restrict__ lse2_w, const float* __restrict__ lse2_b,
    const float* __restrict__ lse2_g, const float* __restrict__ lse2_bt,
    const float* __restrict__ p1_g, const float* __restrict__ p1_bt,
    const float* __restrict__ p2_sw, const float* __restrict__ p2_w,
    const float* __restrict__ p2_b, float* __restrict__ ws) {
    __shared__ float an[24], dc3[24], dcon[8], p1sc[8], p1sh[8],
        sws[64], pws[256], pbs[16];
    const int tid = threadIdx.x;
    if (tid < 8) {
        const int c = tid;
        const float* w = lse2_w + c * 10;
        float sc, sh;
        bn_from_enc(ws + WS_ENC_M, w, lse2_b[c], lse2_g[c], lse2_bt[c], sc, sh);
#pragma unroll
        for (int i = 0; i < 3; i++) {
            an[c * 3 + i] = sc * (w[3 + i] - w[6 + i]);
            dc3[c * 3 + i] = sc * (w[i] + w[6 + i]);
        }
        dcon[c] = sc * (lse2_b[c] + w[9]) + sh;
    } else if (tid < 16) {  // bn_p1 from raw sums
        const int c = tid - 8;
        const float cP = 1.f / (float)NP;
        float m = ws[WS_S_Y2 + c] * cP, v = ws[WS_SS_Y2 + c] * cP - m * m;
        float sc = p1_g[c] * rsqrtf(v + BN_EPS);
        p1sc[c] = sc; p1sh[c] = p1_bt[c] - m * sc;
    }
    if (tid < 64) sws[tid] = p2_sw[(tid >> 3) * 16 + (tid & 7)];
    if (tid < 256) pws[tid] = p2_w[tid];
    if (tid < 16) pbs[tid] = p2_b[tid];
    __syncthreads();

    const int p = blockIdx.x * 256 + tid;
    const int boff = (p >> 16) << 16;
    const float4 me = c4[p];
    float d[8];
#pragma unroll
    for (int c = 0; c < 8; c++)
        d[c] = dc3[c * 3] * me.x + dc3[c * 3 + 1] * me.y + dc3[c * 3 + 2] * me.z + dcon[c];
    const int4* ip = (const int4*)idx + p * 4;
    float l[8] = {}, ac[8] = {};
#pragma unroll
    for (int q = 0; q < 4; q++) {
        int4 v = ip[q];
        int jj[4] = {v.x, v.y, v.z, v.w};
#pragma unroll
        for (int e = 0; e < 4; e++) {
            const float4 nn = c4[boff + jj[e]];
            float h[8];
#pragma unroll
            for (int c = 0; c < 8; c++) {
                float y = an[c * 3] * nn.x + an[c * 3 + 1] * nn.y + an[c * 3 + 2] * nn.z + d[c];
                h[c] = y > 0.f ? y : 0.f;
            }
#pragma unroll
            for (int o = 0; o < 8; o++) {
                float s = 0.f;
#pragma unroll
                for (int i = 0; i < 8; i++) s += h[i] * sws[o * 8 + i];
                float e2 = __expf(s);
                l[o] += e2; ac[o] += e2 * h[o];
            }
        }
    }
    float agg[16];
#pragma unroll
    for (int o = 0; o < 8; o++) agg[o] = ac[o] / l[o];
#pragma unroll
    for (int c = 0; c < 8; c++) {
        float y = ws[WS_Y2 + c * NP + p] * p1sc[c] + p1sh[c];
        agg[8 + c] = y > 0.f ? y : 0.f;
    }
    float st[32];
#pragma unroll
    for (int c = 0; c < 16; c++) {
        float y = pbs[c];
#pragma unroll
        for (int o = 0; o < 16; o++) y += agg[o] * pws[c * 16 + o];
        ws[WS_Y4 + c * NP + p] = y;
        st[c] = y; st[16 + c] = y * y;
    }
    blockReduceAtomic<32>(st, ws + WS_S_Y4);
}

// ---------------- Kernel 5: x4 = relu(bn(y4)); out = leaky(w2@x4 + b2 + bn(sc_w@feats))
__global__ __launch_bounds__(256) void k_final(
    const float* __restrict__ feats, const float* __restrict__ w2,
    const float* __restrict__ b2, const float* __restrict__ sc_w,
    const float* __restrict__ sc_b, const float* __restrict__ p2_g,
    const float* __restrict__ p2_bt, const float* __restrict__ sc_g,
    const float* __restrict__ sc_bt, const float* __restrict__ ws,
    float* __restrict__ out) {
    __shared__ float w2s[512], b2s[32], scws[256], scbs[32],
        p2sc[16], p2sh[16], scsc[32], scsh[32];
    const int tid = threadIdx.x;
    for (int i = tid; i < 512; i += 256) w2s[i] = w2[i];
    if (tid < 256) scws[tid] = sc_w[tid];
    if (tid < 32) {
        b2s[tid] = b2[tid]; scbs[tid] = sc_b[tid];
        // shortcut bn from feature moments
        const int c = tid;
        const float* w = sc_w + c * 8;
        const float* S = ws + WS_SC_M;
        float lin = 0.f;
#pragma unroll
        for (int i = 0; i < 8; i++) lin += w[i] * S[i];
        float quad = 0.f;
        int t2 = 0;
#pragma unroll
        for (int i = 0; i < 8; i++)
#pragma unroll
            for (int j = i; j < 8; j++) {
                const float mm = S[8 + t2++];
                quad += (i == j ? 1.f : 2.f) * w[i] * w[j] * mm;
            }
        const float cnt = (float)NP;
        const float bb = sc_b[c];
        const float sum = lin + cnt * bb;
        const float ss = quad + 2.f * bb * lin + cnt * bb * bb;
        const float m = sum / cnt, v = ss / cnt - m * m;
        const float sc = sc_g[c] * rsqrtf(v + BN_EPS);
        scsc[c] = sc; scsh[c] = sc_bt[c] - m * sc;
    }
    if (tid < 16) {
        const int c = tid;
        const float cP = 1.f / (float)NP;
        float m = ws[WS_S_Y4 + c] * cP, v = ws[WS_SS_Y4 + c] * cP - m * m;
        float sc = p2_g[c] * rsqrtf(v + BN_EPS);
        p2sc[c] = sc; p2sh[c] = p2_bt[c] - m * sc;
    }
    __syncthreads();

    const int p = blockIdx.x * 256 + tid;
    const int b = p >> 16;
    const int n = p & (NN - 1);
    float x4[16];
#pragma unroll
    for (int c = 0; c < 16; c++) {
        float y = ws[WS_Y4 + c * NP + p] * p2sc[c] + p2sh[c];
        x4[c] = y > 0.f ? y : 0.f;
    }
    float f[8];
#pragma unroll
    for (int i = 0; i < 8; i++) f[i] = feats[(b * 8 + i) * NN + n];
#pragma unroll
    for (int c = 0; c < 32; c++) {
        float s = scbs[c];
#pragma unroll
        for (int i = 0; i < 8; i++) s += f[i] * scws[c * 8 + i];
        s = s * scsc[c] + scsh[c];  // bn, no activation
        float m = b2s[c];
#pragma unroll
        for (int o = 0; o < 16; o++) m += x4[o] * w2s[c * 16 + o];
        float v = m + s;
        out[(b * 32 + c) * NN + n] = v > 0.f ? v : 0.01f * v;  // LeakyReLU(0.01)
    }
}

extern "C" void kernel_launch(void* const* d_in, const int* in_sizes, int n_in,
                              void* d_out, int out_size, void* d_ws, size_t ws_size,
                              hipStream_t stream) {
    (void)in_sizes; (void)n_in; (void)out_size; (void)ws_size;
    const float* coords = (const float*)d_in[0];
    const float* features = (const float*)d_in[1];
    const int* idx = (const int*)d_in[2];
    const float* w1 = (const float*)d_in[3];
    const float* b1 = (const float*)d_in[4];
    const float* lse1_w = (const float*)d_in[5];
    const float* lse1_b = (const float*)d_in[6];
    const float* lse1_g = (const float*)d_in[7];
    const float* lse1_bt = (const float*)d_in[8];
    const float* p1_sw = (const float*)d_in[9];
    const float* p1_w = (const float*)d_in[10];
    const float* p1_b = (const float*)d_in[11];
    const float* p1_g = (const float*)d_in[12];
    const float* p1_bt = (const float*)d_in[13];
    const float* lse2_w = (const float*)d_in[14];
    const float* lse2_b = (const float*)d_in[15];
    const float* lse2_g = (const float*)d_in[16];
    const float* lse2_bt = (const float*)d_in[17];
    const float* p2_sw = (const float*)d_in[18];
    const float* p2_w = (const float*)d_in[19];
    const float* p2_b = (const float*)d_in[20];
    const float* p2_g = (const float*)d_in[21];
    const float* p2_bt = (const float*)d_in[22];
    const float* w2 = (const float*)d_in[23];
    const float* b2 = (const float*)d_in[24];
    const float* sc_w = (const float*)d_in[25];
    const float* sc_b = (const float*)d_in[26];
    const float* sc_g = (const float*)d_in[27];
    const float* sc_bt = (const float*)d_in[28];
    float* ws = (float*)d_ws;
    float* out = (float*)d_out;
    float4* c4 = (float4*)d_out;  // scratch: k_final overwrites all of d_out later

    const int NBLK = NP / 256;
    hipMemsetAsync(ws, 0, 144 * sizeof(float), stream);
    k_prep<<<NBLK, 256, 0, stream>>>(coords, features, c4, ws);
    k_stats<<<NBLK, 256, 0, stream>>>(c4, idx, ws);
    k_pool1<<<NBLK, 256, 0, stream>>>(c4, features, idx, w1, b1, lse1_w, lse1_b,
                                      lse1_g, lse1_bt, p1_sw, p1_w, p1_b, ws);
    k_pool2<<<NBLK, 256, 0, stream>>>(c4, idx, lse2_w, lse2_b, lse2_g, lse2_bt,
                                      p1_g, p1_bt, p2_sw, p2_w, p2_b, ws);
    k_final<<<NBLK, 256, 0, stream>>>(features, w2, b2, sc_w, sc_b, p2_g, p2_bt,
                                      sc_g, sc_bt, ws, out);
}

// Round 4
// 620.024 us; speedup vs baseline: 1.0336x; 1.0336x over previous
//
#include <hip/hip_runtime.h>

#define NB 4
#define NN 65536
#define NK 16
#define NP (NB * NN)   // 262144 points
#define BN_EPS 1e-6f

// ---- workspace layout (floats) ----
// raw sums (zeroed each launch):
// enc moments over all (p,k), basis [cx,cy,cz,nx,ny,nz,1]:
//   [0..2] S_c(x16/pt)  [3..5] S_n  [6..11] M_cc upper  [12..20] M_cn 3x3  [21..26] M_nn upper
#define WS_ENC_M   0    // 27 floats
#define WS_SC_M    32   // S_f[8] @32, M_ff upper-tri 36 @40  (44 floats)
#define WS_S_Y2    96   // 8  pool1 conv sum
#define WS_SS_Y2   104  // 8
#define WS_S_Y4    112  // 16 pool2 conv sum
#define WS_SS_Y4   128  // 16 -> raw stats end at 144
// big buffers, channel-major [c][p] for coalesced access
#define WS_Y2      1024             // NP*8  floats (8 MB)
#define WS_Y4      (1024 + NP * 8)  // NP*16 floats (16 MB)

template <int NCH>
__device__ inline void blockReduceAtomic(float (&v)[NCH], float* __restrict__ dst) {
    __shared__ float red[4][NCH];
    const int lane = threadIdx.x & 63;
    const int wv = threadIdx.x >> 6;
#pragma unroll
    for (int c = 0; c < NCH; c++) {
        float x = v[c];
#pragma unroll
        for (int off = 32; off > 0; off >>= 1) x += __shfl_xor(x, off, 64);
        if (lane == 0) red[wv][c] = x;
    }
    __syncthreads();
    for (int c = threadIdx.x; c < NCH; c += 256)
        atomicAdd(dst + c, red[0][c] + red[1][c] + red[2][c] + red[3][c]);
}

// bn scale/shift for an lse conv channel from enc moments. w points at 10 weights.
__device__ inline void bn_from_enc(const float* __restrict__ M, const float* __restrict__ w,
                                   float b, float g, float bt, float& sc, float& sh) {
    float u[6];
    u[0] = w[0] + w[6]; u[1] = w[1] + w[7]; u[2] = w[2] + w[8];
    u[3] = w[3] - w[6]; u[4] = w[4] - w[7]; u[5] = w[5] - w[8];
    const float beta = b + w[9];
    float lin = 0.f;
#pragma unroll
    for (int i = 0; i < 6; i++) lin += u[i] * M[i];
    float quad = u[0] * u[0] * M[6] + 2.f * u[0] * u[1] * M[7] + 2.f * u[0] * u[2] * M[8]
               + u[1] * u[1] * M[9] + 2.f * u[1] * u[2] * M[10] + u[2] * u[2] * M[11];
#pragma unroll
    for (int i = 0; i < 3; i++)
#pragma unroll
        for (int j = 0; j < 3; j++) quad += 2.f * u[i] * u[3 + j] * M[12 + i * 3 + j];
    quad += u[3] * u[3] * M[21] + 2.f * u[3] * u[4] * M[22] + 2.f * u[3] * u[5] * M[23]
          + u[4] * u[4] * M[24] + 2.f * u[4] * u[5] * M[25] + u[5] * u[5] * M[26];
    const float cnt = (float)NP * (float)NK;
    const float sum = lin + cnt * beta;
    const float ss = quad + 2.f * beta * lin + cnt * beta * beta;
    const float m = sum / cnt, v = ss / cnt - m * m;
    sc = g * rsqrtf(v + BN_EPS);
    sh = bt - m * sc;
}

// ---------------- Kernel 1: enc moments + shortcut feat moments (gathers from coords input)
__global__ __launch_bounds__(256, 4) void k_stats(
    const float* __restrict__ coords, const float* __restrict__ feats,
    const int* __restrict__ idx, float* __restrict__ ws) {
    const int tid = threadIdx.x;
    const int p = blockIdx.x * 256 + tid;
    const int b = p >> 16;
    const int n = p & (NN - 1);

    // shortcut feature moments first (retire registers before nbr loop)
    {
        float accf[44];
        float f[8];
#pragma unroll
        for (int i = 0; i < 8; i++) f[i] = feats[(b * 8 + i) * NN + n];
#pragma unroll
        for (int i = 0; i < 8; i++) accf[i] = f[i];
        int t2 = 8;
#pragma unroll
        for (int i = 0; i < 8; i++)
#pragma unroll
            for (int j = i; j < 8; j++) accf[t2++] = f[i] * f[j];
        blockReduceAtomic<44>(accf, ws + WS_SC_M);
    }

    const float cx = coords[3 * p], cy = coords[3 * p + 1], cz = coords[3 * p + 2];
    const float* cb = coords + b * NN * 3;
    const int4* ip = (const int4*)idx + p * 4;
    float sn0 = 0.f, sn1 = 0.f, sn2 = 0.f;
    float m00 = 0.f, m01 = 0.f, m02 = 0.f, m11 = 0.f, m12 = 0.f, m22 = 0.f;
#pragma unroll
    for (int q = 0; q < 4; q++) {
        int4 v = ip[q];
        int jj[4] = {v.x, v.y, v.z, v.w};
#pragma unroll
        for (int e = 0; e < 4; e++) {
            const int j = jj[e];
            const float nx = cb[3 * j], ny = cb[3 * j + 1], nz = cb[3 * j + 2];
            sn0 += nx; sn1 += ny; sn2 += nz;
            m00 += nx * nx; m01 += nx * ny; m02 += nx * nz;
            m11 += ny * ny; m12 += ny * nz; m22 += nz * nz;
        }
    }
    float acc[27];
    acc[0] = 16.f * cx; acc[1] = 16.f * cy; acc[2] = 16.f * cz;
    acc[3] = sn0; acc[4] = sn1; acc[5] = sn2;
    acc[6] = 16.f * cx * cx; acc[7] = 16.f * cx * cy; acc[8] = 16.f * cx * cz;
    acc[9] = 16.f * cy * cy; acc[10] = 16.f * cy * cz; acc[11] = 16.f * cz * cz;
    acc[12] = cx * sn0; acc[13] = cx * sn1; acc[14] = cx * sn2;
    acc[15] = cy * sn0; acc[16] = cy * sn1; acc[17] = cy * sn2;
    acc[18] = cz * sn0; acc[19] = cz * sn1; acc[20] = cz * sn2;
    acc[21] = m00; acc[22] = m01; acc[23] = m02;
    acc[24] = m11; acc[25] = m12; acc[26] = m22;
    blockReduceAtomic<27>(acc, ws + WS_ENC_M);
}

// ---------------- Kernel 2: mlp1 + lse1 + pool1 -> y2 (pre-BN), bn_p1 raw sums
__global__ __launch_bounds__(256, 4) void k_pool1(
    const float* __restrict__ coords, const float* __restrict__ feats,
    const int* __restrict__ idx,
    const float* __restrict__ w1, const float* __restrict__ b1,
    const float* __restrict__ lse1_w, const float* __restrict__ lse1_b,
    const float* __restrict__ lse1_g, const float* __restrict__ lse1_bt,
    const float* __restrict__ p1_sw, const float* __restrict__ p1_w,
    const float* __restrict__ p1_b, float* __restrict__ ws) {
    // an: bn-folded neighbor weights; dc3/dcon: per-point affine precursor
    __shared__ float an[24], dc3[24], dcon[8], sws[64], pws[128], pbs[8], w1s[64], b1s[8];
    const int tid = threadIdx.x;
    if (tid < 8) {
        const int c = tid;
        const float* w = lse1_w + c * 10;
        float sc, sh;
        bn_from_enc(ws + WS_ENC_M, w, lse1_b[c], lse1_g[c], lse1_bt[c], sc, sh);
#pragma unroll
        for (int i = 0; i < 3; i++) {
            an[c * 3 + i] = sc * (w[3 + i] - w[6 + i]);
            dc3[c * 3 + i] = sc * (w[i] + w[6 + i]);
        }
        dcon[c] = sc * (lse1_b[c] + w[9]) + sh;
        b1s[c] = b1[c]; pbs[c] = p1_b[c];
    }
    if (tid < 64) {
        w1s[tid] = w1[tid];
        sws[tid] = p1_sw[(tid >> 3) * 16 + (tid & 7)];  // only 8x8 block matters
    }
    if (tid < 128) pws[tid] = p1_w[tid];
    __syncthreads();

    const int p = blockIdx.x * 256 + tid;
    const int b = p >> 16;
    const int n = p & (NN - 1);
    const float cx = coords[3 * p], cy = coords[3 * p + 1], cz = coords[3 * p + 2];
    const float* cb = coords + b * NN * 3;
    float d[8];
#pragma unroll
    for (int c = 0; c < 8; c++)
        d[c] = dc3[c * 3] * cx + dc3[c * 3 + 1] * cy + dc3[c * 3 + 2] * cz + dcon[c];
    const int4* ip = (const int4*)idx + p * 4;
    float l[8] = {}, ac[8] = {};
#pragma unroll
    for (int q = 0; q < 4; q++) {
        int4 v = ip[q];
        int jj[4] = {v.x, v.y, v.z, v.w};
#pragma unroll
        for (int e = 0; e < 4; e++) {
            const int j = jj[e];
            const float nx = cb[3 * j], ny = cb[3 * j + 1], nz = cb[3 * j + 2];
            float h[8];
#pragma unroll
            for (int c = 0; c < 8; c++) {
                float y = an[c * 3] * nx + an[c * 3 + 1] * ny + an[c * 3 + 2] * nz + d[c];
                h[c] = y > 0.f ? y : 0.f;
            }
#pragma unroll
            for (int o = 0; o < 8; o++) {
                float s = 0.f;
#pragma unroll
                for (int i = 0; i < 8; i++) s += h[i] * sws[o * 8 + i];
                float e2 = __expf(s);  // k-constant part of score cancels in softmax
                l[o] += e2; ac[o] += e2 * h[o];
            }
        }
    }
    // epilogue: mlp1 (broadcast channels pool to themselves), pool1 conv
    float f[8];
#pragma unroll
    for (int i = 0; i < 8; i++) f[i] = feats[(b * 8 + i) * NN + n];
    float agg[16];
#pragma unroll
    for (int o = 0; o < 8; o++) agg[o] = ac[o] / l[o];
#pragma unroll
    for (int jq = 0; jq < 8; jq++) {
        float y = b1s[jq];
#pragma unroll
        for (int i = 0; i < 8; i++) y += f[i] * w1s[jq * 8 + i];
        agg[8 + jq] = y > 0.f ? y : 0.2f * y;  // LeakyReLU(0.2)
    }
    float st[16];
#pragma unroll
    for (int c = 0; c < 8; c++) {
        float y = pbs[c];
#pragma unroll
        for (int o = 0; o < 16; o++) y += agg[o] * pws[c * 16 + o];
        ws[WS_Y2 + c * NP + p] = y;
        st[c] = y; st[8 + c] = y * y;
    }
    blockReduceAtomic<16>(st, ws + WS_S_Y2);
}

// ---------------- Kernel 3: bn_p1+relu -> x2, lse2 + pool2 -> y4 (pre-BN), bn_p2 raw sums
__global__ __launch_bounds__(256, 4) void k_pool2(
    const float* __restrict__ coords, const int* __restrict__ idx,
    const float* __restrict__ lse2_w, const float* __restrict__ lse2_b,
    const float* __restrict__ lse2_g, const float* __restrict__ lse2_bt,
    const float* __restrict__ p1_g, const float* __restrict__ p1_bt,
    const float* __restrict__ p2_sw, const float* __restrict__ p2_w,
    const float* __restrict__ p2_b, float* __restrict__ ws) {
    __shared__ float an[24], dc3[24], dcon[8], p1sc[8], p1sh[8],
        sws[64], pws[256], pbs[16];
    const int tid = threadIdx.x;
    if (tid < 8) {
        const int c = tid;
        const float* w = lse2_w + c * 10;
        float sc, sh;
        bn_from_enc(ws + WS_ENC_M, w, lse2_b[c], lse2_g[c], lse2_bt[c], sc, sh);
#pragma unroll
        for (int i = 0; i < 3; i++) {
            an[c * 3 + i] = sc * (w[3 + i] - w[6 + i]);
            dc3[c * 3 + i] = sc * (w[i] + w[6 + i]);
        }
        dcon[c] = sc * (lse2_b[c] + w[9]) + sh;
    } else if (tid < 16) {  // bn_p1 from raw sums
        const int c = tid - 8;
        const float cP = 1.f / (float)NP;
        float m = ws[WS_S_Y2 + c] * cP, v = ws[WS_SS_Y2 + c] * cP - m * m;
        float sc = p1_g[c] * rsqrtf(v + BN_EPS);
        p1sc[c] = sc; p1sh[c] = p1_bt[c] - m * sc;
    }
    if (tid < 64) sws[tid] = p2_sw[(tid >> 3) * 16 + (tid & 7)];
    if (tid < 256) pws[tid] = p2_w[tid];
    if (tid < 16) pbs[tid] = p2_b[tid];
    __syncthreads();

    const int p = blockIdx.x * 256 + tid;
    const int b = p >> 16;
    const float cx = coords[3 * p], cy = coords[3 * p + 1], cz = coords[3 * p + 2];
    const float* cb = coords + b * NN * 3;
    float d[8];
#pragma unroll
    for (int c = 0; c < 8; c++)
        d[c] = dc3[c * 3] * cx + dc3[c * 3 + 1] * cy + dc3[c * 3 + 2] * cz + dcon[c];
    const int4* ip = (const int4*)idx + p * 4;
    float l[8] = {}, ac[8] = {};
#pragma unroll
    for (int q = 0; q < 4; q++) {
        int4 v = ip[q];
        int jj[4] = {v.x, v.y, v.z, v.w};
#pragma unroll
        for (int e = 0; e < 4; e++) {
            const int j = jj[e];
            const float nx = cb[3 * j], ny = cb[3 * j + 1], nz = cb[3 * j + 2];
            float h[8];
#pragma unroll
            for (int c = 0; c < 8; c++) {
                float y = an[c * 3] * nx + an[c * 3 + 1] * ny + an[c * 3 + 2] * nz + d[c];
                h[c] = y > 0.f ? y : 0.f;
            }
#pragma unroll
            for (int o = 0; o < 8; o++) {
                float s = 0.f;
#pragma unroll
                for (int i = 0; i < 8; i++) s += h[i] * sws[o * 8 + i];
                float e2 = __expf(s);
                l[o] += e2; ac[o] += e2 * h[o];
            }
        }
    }
    float agg[16];
#pragma unroll
    for (int o = 0; o < 8; o++) agg[o] = ac[o] / l[o];
#pragma unroll
    for (int c = 0; c < 8; c++) {
        float y = ws[WS_Y2 + c * NP + p] * p1sc[c] + p1sh[c];
        agg[8 + c] = y > 0.f ? y : 0.f;
    }
    float st[32];
#pragma unroll
    for (int c = 0; c < 16; c++) {
        float y = pbs[c];
#pragma unroll
        for (int o = 0; o < 16; o++) y += agg[o] * pws[c * 16 + o];
        ws[WS_Y4 + c * NP + p] = y;
        st[c] = y; st[16 + c] = y * y;
    }
    blockReduceAtomic<32>(st, ws + WS_S_Y4);
}

// ---------------- Kernel 4: x4 = relu(bn(y4)); out = leaky(w2@x4 + b2 + bn(sc_w@feats))
__global__ __launch_bounds__(256) void k_final(
    const float* __restrict__ feats, const float* __restrict__ w2,
    const float* __restrict__ b2, const float* __restrict__ sc_w,
    const float* __restrict__ sc_b, const float* __restrict__ p2_g,
    const float* __restrict__ p2_bt, const float* __restrict__ sc_g,
    const float* __restrict__ sc_bt, const float* __restrict__ ws,
    float* __restrict__ out) {
    __shared__ float w2s[512], b2s[32], scws[256], scbs[32],
        p2sc[16], p2sh[16], scsc[32], scsh[32];
    const int tid = threadIdx.x;
    for (int i = tid; i < 512; i += 256) w2s[i] = w2[i];
    if (tid < 256) scws[tid] = sc_w[tid];
    if (tid < 32) {
        b2s[tid] = b2[tid]; scbs[tid] = sc_b[tid];
        // shortcut bn from feature moments
        const int c = tid;
        const float* w = sc_w + c * 8;
        const float* S = ws + WS_SC_M;
        float lin = 0.f;
#pragma unroll
        for (int i = 0; i < 8; i++) lin += w[i] * S[i];
        float quad = 0.f;
        int t2 = 0;
#pragma unroll
        for (int i = 0; i < 8; i++)
#pragma unroll
            for (int j = i; j < 8; j++) {
                const float mm = S[8 + t2++];
                quad += (i == j ? 1.f : 2.f) * w[i] * w[j] * mm;
            }
        const float cnt = (float)NP;
        const float bb = sc_b[c];
        const float sum = lin + cnt * bb;
        const float ss = quad + 2.f * bb * lin + cnt * bb * bb;
        const float m = sum / cnt, v = ss / cnt - m * m;
        const float sc = sc_g[c] * rsqrtf(v + BN_EPS);
        scsc[c] = sc; scsh[c] = sc_bt[c] - m * sc;
    }
    if (tid < 16) {
        const int c = tid;
        const float cP = 1.f / (float)NP;
        float m = ws[WS_S_Y4 + c] * cP, v = ws[WS_SS_Y4 + c] * cP - m * m;
        float sc = p2_g[c] * rsqrtf(v + BN_EPS);
        p2sc[c] = sc; p2sh[c] = p2_bt[c] - m * sc;
    }
    __syncthreads();

    const int p = blockIdx.x * 256 + tid;
    const int b = p >> 16;
    const int n = p & (NN - 1);
    float x4[16];
#pragma unroll
    for (int c = 0; c < 16; c++) {
        float y = ws[WS_Y4 + c * NP + p] * p2sc[c] + p2sh[c];
        x4[c] = y > 0.f ? y : 0.f;
    }
    float f[8];
#pragma unroll
    for (int i = 0; i < 8; i++) f[i] = feats[(b * 8 + i) * NN + n];
#pragma unroll
    for (int c = 0; c < 32; c++) {
        float s = scbs[c];
#pragma unroll
        for (int i = 0; i < 8; i++) s += f[i] * scws[c * 8 + i];
        s = s * scsc[c] + scsh[c];  // bn, no activation
        float m = b2s[c];
#pragma unroll
        for (int o = 0; o < 16; o++) m += x4[o] * w2s[c * 16 + o];
        float v = m + s;
        out[(b * 32 + c) * NN + n] = v > 0.f ? v : 0.01f * v;  // LeakyReLU(0.01)
    }
}

extern "C" void kernel_launch(void* const* d_in, const int* in_sizes, int n_in,
                              void* d_out, int out_size, void* d_ws, size_t ws_size,
                              hipStream_t stream) {
    (void)in_sizes; (void)n_in; (void)out_size; (void)ws_size;
    const float* coords = (const float*)d_in[0];
    const float* features = (const float*)d_in[1];
    const int* idx = (const int*)d_in[2];
    const float* w1 = (const float*)d_in[3];
    const float* b1 = (const float*)d_in[4];
    const float* lse1_w = (const float*)d_in[5];
    const float* lse1_b = (const float*)d_in[6];
    const float* lse1_g = (const float*)d_in[7];
    const float* lse1_bt = (const float*)d_in[8];
    const float* p1_sw = (const float*)d_in[9];
    const float* p1_w = (const float*)d_in[10];
    const float* p1_b = (const float*)d_in[11];
    const float* p1_g = (const float*)d_in[12];
    const float* p1_bt = (const float*)d_in[13];
    const float* lse2_w = (const float*)d_in[14];
    const float* lse2_b = (const float*)d_in[15];
    const float* lse2_g = (const float*)d_in[16];
    const float* lse2_bt = (const float*)d_in[17];
    const float* p2_sw = (const float*)d_in[18];
    const float* p2_w = (const float*)d_in[19];
    const float* p2_b = (const float*)d_in[20];
    const float* p2_g = (const float*)d_in[21];
    const float* p2_bt = (const float*)d_in[22];
    const float* w2 = (const float*)d_in[23];
    const float* b2 = (const float*)d_in[24];
    const float* sc_w = (const float*)d_in[25];
    const float* sc_b = (const float*)d_in[26];
    const float* sc_g = (const float*)d_in[27];
    const float* sc_bt = (const float*)d_in[28];
    float* ws = (float*)d_ws;
    float* out = (float*)d_out;

    const int NBLK = NP / 256;
    hipMemsetAsync(ws, 0, 144 * sizeof(float), stream);
    k_stats<<<NBLK, 256, 0, stream>>>(coords, features, idx, ws);
    k_pool1<<<NBLK, 256, 0, stream>>>(coords, features, idx, w1, b1, lse1_w, lse1_b,
                                      lse1_g, lse1_bt, p1_sw, p1_w, p1_b, ws);
    k_pool2<<<NBLK, 256, 0, stream>>>(coords, idx, lse2_w, lse2_b, lse2_g, lse2_bt,
                                      p1_g, p1_bt, p2_sw, p2_w, p2_b, ws);
    k_final<<<NBLK, 256, 0, stream>>>(features, w2, b2, sc_w, sc_b, p2_g, p2_bt,
                                      sc_g, sc_bt, ws, out);
}

// Round 6
// 349.115 us; speedup vs baseline: 1.8357x; 1.7760x over previous
//
#include <hip/hip_runtime.h>

#define NB 4
#define NN 65536
#define NK 16
#define NP (NB * NN)   // 262144 points
#define BN_EPS 1e-6f

// ---- workspace layout (floats) ----
// enc moments over all (p,k), basis [cx,cy,cz,nx,ny,nz,1]:
//   [0..2] S_c(x16/pt)  [3..5] S_n  [6..11] M_cc upper  [12..20] M_cn 3x3  [21..26] M_nn upper
#define WS_ENC_M   0    // 27 floats
#define WS_SC_M    32   // S_f[8] @32, M_ff upper-tri 36 @40  (44 floats)
#define WS_S_Y2    96   // 8  pool1 conv sum
#define WS_SS_Y2   104  // 8
#define WS_S_Y4    112  // 16 pool2 conv sum
#define WS_SS_Y4   128  // 16 -> raw stats end at 144
// big buffers, channel-major [c][p] for coalesced access
#define WS_Y2      1024             // NP*8  floats (8 MB)
#define WS_Y4      (1024 + NP * 8)  // NP*16 floats (16 MB)

// NOTE: entry+exit __syncthreads are REQUIRED. The compiler overlays the
// static __shared__ `red` arrays of different template instantiations (and
// other kernel __shared__ arrays) in the same LDS space; without barriers,
// lane-0 writes here race with other waves' outstanding reads of the aliased
// region (caused the R5 intermittent corruption at high occupancy).
template <int NCH>
__device__ inline void blockReduceAtomic(float (&v)[NCH], float* __restrict__ dst) {
    __shared__ float red[4][NCH];
    const int lane = threadIdx.x & 63;
    const int wv = threadIdx.x >> 6;
    __syncthreads();  // all prior LDS reads (possibly aliased with red) done
#pragma unroll
    for (int c = 0; c < NCH; c++) {
        float x = v[c];
#pragma unroll
        for (int off = 32; off > 0; off >>= 1) x += __shfl_xor(x, off, 64);
        if (lane == 0) red[wv][c] = x;
    }
    __syncthreads();
    for (int c = threadIdx.x; c < NCH; c += 256)
        atomicAdd(dst + c, red[0][c] + red[1][c] + red[2][c] + red[3][c]);
    __syncthreads();  // reads of red done before any later aliased writes
}

// bn scale/shift for an lse conv channel from enc moments. w points at 10 weights.
__device__ inline void bn_from_enc(const float* __restrict__ M, const float* __restrict__ w,
                                   float b, float g, float bt, float& sc, float& sh) {
    float u[6];
    u[0] = w[0] + w[6]; u[1] = w[1] + w[7]; u[2] = w[2] + w[8];
    u[3] = w[3] - w[6]; u[4] = w[4] - w[7]; u[5] = w[5] - w[8];
    const float beta = b + w[9];
    float lin = 0.f;
#pragma unroll
    for (int i = 0; i < 6; i++) lin += u[i] * M[i];
    float quad = u[0] * u[0] * M[6] + 2.f * u[0] * u[1] * M[7] + 2.f * u[0] * u[2] * M[8]
               + u[1] * u[1] * M[9] + 2.f * u[1] * u[2] * M[10] + u[2] * u[2] * M[11];
#pragma unroll
    for (int i = 0; i < 3; i++)
#pragma unroll
        for (int j = 0; j < 3; j++) quad += 2.f * u[i] * u[3 + j] * M[12 + i * 3 + j];
    quad += u[3] * u[3] * M[21] + 2.f * u[3] * u[4] * M[22] + 2.f * u[3] * u[5] * M[23]
          + u[4] * u[4] * M[24] + 2.f * u[4] * u[5] * M[25] + u[5] * u[5] * M[26];
    const float cnt = (float)NP * (float)NK;
    const float sum = lin + cnt * beta;
    const float ss = quad + 2.f * beta * lin + cnt * beta * beta;
    const float m = sum / cnt, v = ss / cnt - m * m;
    sc = g * rsqrtf(v + BN_EPS);
    sh = bt - m * sc;
}

// ---------------- Kernel 1: enc moments + shortcut feat moments
__global__ __launch_bounds__(256) void k_stats(
    const float* __restrict__ coords, const float* __restrict__ feats,
    const int* __restrict__ idx, float* __restrict__ ws) {
    const int tid = threadIdx.x;
    const int p = blockIdx.x * 256 + tid;
    const int b = p >> 16;
    const int n = p & (NN - 1);

    // shortcut feature moments first (retire registers before nbr loop)
    {
        float accf[44];
        float f[8];
#pragma unroll
        for (int i = 0; i < 8; i++) f[i] = feats[(b * 8 + i) * NN + n];
#pragma unroll
        for (int i = 0; i < 8; i++) accf[i] = f[i];
        int t2 = 8;
#pragma unroll
        for (int i = 0; i < 8; i++)
#pragma unroll
            for (int j = i; j < 8; j++) accf[t2++] = f[i] * f[j];
        blockReduceAtomic<44>(accf, ws + WS_SC_M);
    }

    const float cx = coords[3 * p], cy = coords[3 * p + 1], cz = coords[3 * p + 2];
    const float* cb = coords + b * NN * 3;
    const int4* ip = (const int4*)idx + p * 4;
    float sn0 = 0.f, sn1 = 0.f, sn2 = 0.f;
    float m00 = 0.f, m01 = 0.f, m02 = 0.f, m11 = 0.f, m12 = 0.f, m22 = 0.f;
#pragma unroll
    for (int q = 0; q < 4; q++) {
        int4 v = ip[q];
        int jj[4] = {v.x, v.y, v.z, v.w};
#pragma unroll
        for (int e = 0; e < 4; e++) {
            const int j = jj[e];
            const float nx = cb[3 * j], ny = cb[3 * j + 1], nz = cb[3 * j + 2];
            sn0 += nx; sn1 += ny; sn2 += nz;
            m00 += nx * nx; m01 += nx * ny; m02 += nx * nz;
            m11 += ny * ny; m12 += ny * nz; m22 += nz * nz;
        }
    }
    float acc[27];
    acc[0] = 16.f * cx; acc[1] = 16.f * cy; acc[2] = 16.f * cz;
    acc[3] = sn0; acc[4] = sn1; acc[5] = sn2;
    acc[6] = 16.f * cx * cx; acc[7] = 16.f * cx * cy; acc[8] = 16.f * cx * cz;
    acc[9] = 16.f * cy * cy; acc[10] = 16.f * cy * cz; acc[11] = 16.f * cz * cz;
    acc[12] = cx * sn0; acc[13] = cx * sn1; acc[14] = cx * sn2;
    acc[15] = cy * sn0; acc[16] = cy * sn1; acc[17] = cy * sn2;
    acc[18] = cz * sn0; acc[19] = cz * sn1; acc[20] = cz * sn2;
    acc[21] = m00; acc[22] = m01; acc[23] = m02;
    acc[24] = m11; acc[25] = m12; acc[26] = m22;
    blockReduceAtomic<27>(acc, ws + WS_ENC_M);
}

// ---------------- Kernel 2: mlp1 + lse1 + pool1 -> y2 (pre-BN), bn_p1 raw sums
__global__ __launch_bounds__(256) void k_pool1(
    const float* __restrict__ coords, const float* __restrict__ feats,
    const int* __restrict__ idx,
    const float* __restrict__ w1, const float* __restrict__ b1,
    const float* __restrict__ lse1_w, const float* __restrict__ lse1_b,
    const float* __restrict__ lse1_g, const float* __restrict__ lse1_bt,
    const float* __restrict__ p1_sw, const float* __restrict__ p1_w,
    const float* __restrict__ p1_b, float* __restrict__ ws) {
    // an: bn-folded neighbor weights; dc3/dcon: per-point affine precursor
    __shared__ float an[24], dc3[24], dcon[8], sws[64], pws[128], pbs[8], w1s[64], b1s[8];
    const int tid = threadIdx.x;
    if (tid < 8) {
        const int c = tid;
        const float* w = lse1_w + c * 10;
        float sc, sh;
        bn_from_enc(ws + WS_ENC_M, w, lse1_b[c], lse1_g[c], lse1_bt[c], sc, sh);
#pragma unroll
        for (int i = 0; i < 3; i++) {
            an[c * 3 + i] = sc * (w[3 + i] - w[6 + i]);
            dc3[c * 3 + i] = sc * (w[i] + w[6 + i]);
        }
        dcon[c] = sc * (lse1_b[c] + w[9]) + sh;
        b1s[c] = b1[c]; pbs[c] = p1_b[c];
    }
    if (tid < 64) {
        w1s[tid] = w1[tid];
        sws[tid] = p1_sw[(tid >> 3) * 16 + (tid & 7)];  // only 8x8 block matters
    }
    if (tid < 128) pws[tid] = p1_w[tid];
    __syncthreads();

    const int p = blockIdx.x * 256 + tid;
    const int b = p >> 16;
    const int n = p & (NN - 1);
    const float cx = coords[3 * p], cy = coords[3 * p + 1], cz = coords[3 * p + 2];
    const float* cb = coords + b * NN * 3;
    float d[8];
#pragma unroll
    for (int c = 0; c < 8; c++)
        d[c] = dc3[c * 3] * cx + dc3[c * 3 + 1] * cy + dc3[c * 3 + 2] * cz + dcon[c];
    const int4* ip = (const int4*)idx + p * 4;
    float l[8] = {}, ac[8] = {};
#pragma unroll
    for (int q = 0; q < 4; q++) {
        int4 v = ip[q];
        int jj[4] = {v.x, v.y, v.z, v.w};
#pragma unroll
        for (int e = 0; e < 4; e++) {
            const int j = jj[e];
            const float nx = cb[3 * j], ny = cb[3 * j + 1], nz = cb[3 * j + 2];
            float h[8];
#pragma unroll
            for (int c = 0; c < 8; c++) {
                float y = an[c * 3] * nx + an[c * 3 + 1] * ny + an[c * 3 + 2] * nz + d[c];
                h[c] = y > 0.f ? y : 0.f;
            }
#pragma unroll
            for (int o = 0; o < 8; o++) {
                float s = 0.f;
#pragma unroll
                for (int i = 0; i < 8; i++) s += h[i] * sws[o * 8 + i];
                float e2 = __expf(s);  // k-constant part of score cancels in softmax
                l[o] += e2; ac[o] += e2 * h[o];
            }
        }
    }
    // epilogue: mlp1 (broadcast channels pool to themselves), pool1 conv
    float f[8];
#pragma unroll
    for (int i = 0; i < 8; i++) f[i] = feats[(b * 8 + i) * NN + n];
    float agg[16];
#pragma unroll
    for (int o = 0; o < 8; o++) agg[o] = ac[o] / l[o];
#pragma unroll
    for (int jq = 0; jq < 8; jq++) {
        float y = b1s[jq];
#pragma unroll
        for (int i = 0; i < 8; i++) y += f[i] * w1s[jq * 8 + i];
        agg[8 + jq] = y > 0.f ? y : 0.2f * y;  // LeakyReLU(0.2)
    }
    float st[16];
#pragma unroll
    for (int c = 0; c < 8; c++) {
        float y = pbs[c];
#pragma unroll
        for (int o = 0; o < 16; o++) y += agg[o] * pws[c * 16 + o];
        ws[WS_Y2 + c * NP + p] = y;
        st[c] = y; st[8 + c] = y * y;
    }
    blockReduceAtomic<16>(st, ws + WS_S_Y2);
}

// ---------------- Kernel 3: bn_p1+relu -> x2, lse2 + pool2 -> y4 (pre-BN), bn_p2 raw sums
__global__ __launch_bounds__(256) void k_pool2(
    const float* __restrict__ coords, const int* __restrict__ idx,
    const float* __restrict__ lse2_w, const float* __restrict__ lse2_b,
    const float* __restrict__ lse2_g, const float* __restrict__ lse2_bt,
    const float* __restrict__ p1_g, const float* __restrict__ p1_bt,
    const float* __restrict__ p2_sw, const float* __restrict__ p2_w,
    const float* __restrict__ p2_b, float* __restrict__ ws) {
    __shared__ float an[24], dc3[24], dcon[8], p1sc[8], p1sh[8],
        sws[64], pws[256], pbs[16];
    const int tid = threadIdx.x;
    if (tid < 8) {
        const int c = tid;
        const float* w = lse2_w + c * 10;
        float sc, sh;
        bn_from_enc(ws + WS_ENC_M, w, lse2_b[c], lse2_g[c], lse2_bt[c], sc, sh);
#pragma unroll
        for (int i = 0; i < 3; i++) {
            an[c * 3 + i] = sc * (w[3 + i] - w[6 + i]);
            dc3[c * 3 + i] = sc * (w[i] + w[6 + i]);
        }
        dcon[c] = sc * (lse2_b[c] + w[9]) + sh;
    } else if (tid < 16) {  // bn_p1 from raw sums
        const int c = tid - 8;
        const float cP = 1.f / (float)NP;
        float m = ws[WS_S_Y2 + c] * cP, v = ws[WS_SS_Y2 + c] * cP - m * m;
        float sc = p1_g[c] * rsqrtf(v + BN_EPS);
        p1sc[c] = sc; p1sh[c] = p1_bt[c] - m * sc;
    }
    if (tid < 64) sws[tid] = p2_sw[(tid >> 3) * 16 + (tid & 7)];
    if (tid < 256) pws[tid] = p2_w[tid];
    if (tid < 16) pbs[tid] = p2_b[tid];
    __syncthreads();

    const int p = blockIdx.x * 256 + tid;
    const int b = p >> 16;
    const float cx = coords[3 * p], cy = coords[3 * p + 1], cz = coords[3 * p + 2];
    const float* cb = coords + b * NN * 3;
    float d[8];
#pragma unroll
    for (int c = 0; c < 8; c++)
        d[c] = dc3[c * 3] * cx + dc3[c * 3 + 1] * cy + dc3[c * 3 + 2] * cz + dcon[c];
    const int4* ip = (const int4*)idx + p * 4;
    float l[8] = {}, ac[8] = {};
#pragma unroll
    for (int q = 0; q < 4; q++) {
        int4 v = ip[q];
        int jj[4] = {v.x, v.y, v.z, v.w};
#pragma unroll
        for (int e = 0; e < 4; e++) {
            const int j = jj[e];
            const float nx = cb[3 * j], ny = cb[3 * j + 1], nz = cb[3 * j + 2];
            float h[8];
#pragma unroll
            for (int c = 0; c < 8; c++) {
                float y = an[c * 3] * nx + an[c * 3 + 1] * ny + an[c * 3 + 2] * nz + d[c];
                h[c] = y > 0.f ? y : 0.f;
            }
#pragma unroll
            for (int o = 0; o < 8; o++) {
                float s = 0.f;
#pragma unroll
                for (int i = 0; i < 8; i++) s += h[i] * sws[o * 8 + i];
                float e2 = __expf(s);
                l[o] += e2; ac[o] += e2 * h[o];
            }
        }
    }
    float agg[16];
#pragma unroll
    for (int o = 0; o < 8; o++) agg[o] = ac[o] / l[o];
#pragma unroll
    for (int c = 0; c < 8; c++) {
        float y = ws[WS_Y2 + c * NP + p] * p1sc[c] + p1sh[c];
        agg[8 + c] = y > 0.f ? y : 0.f;
    }
    float st[32];
#pragma unroll
    for (int c = 0; c < 16; c++) {
        float y = pbs[c];
#pragma unroll
        for (int o = 0; o < 16; o++) y += agg[o] * pws[c * 16 + o];
        ws[WS_Y4 + c * NP + p] = y;
        st[c] = y; st[16 + c] = y * y;
    }
    blockReduceAtomic<32>(st, ws + WS_S_Y4);
}

// ---------------- Kernel 4: x4 = relu(bn(y4)); out = leaky(w2@x4 + b2 + bn(sc_w@feats))
__global__ __launch_bounds__(256) void k_final(
    const float* __restrict__ feats, const float* __restrict__ w2,
    const float* __restrict__ b2, const float* __restrict__ sc_w,
    const float* __restrict__ sc_b, const float* __restrict__ p2_g,
    const float* __restrict__ p2_bt, const float* __restrict__ sc_g,
    const float* __restrict__ sc_bt, const float* __restrict__ ws,
    float* __restrict__ out) {
    __shared__ float w2s[512], b2s[32], scws[256], scbs[32],
        p2sc[16], p2sh[16], scsc[32], scsh[32];
    const int tid = threadIdx.x;
    for (int i = tid; i < 512; i += 256) w2s[i] = w2[i];
    if (tid < 256) scws[tid] = sc_w[tid];
    if (tid < 32) {
        b2s[tid] = b2[tid]; scbs[tid] = sc_b[tid];
        // shortcut bn from feature moments
        const int c = tid;
        const float* w = sc_w + c * 8;
        const float* S = ws + WS_SC_M;
        float lin = 0.f;
#pragma unroll
        for (int i = 0; i < 8; i++) lin += w[i] * S[i];
        float quad = 0.f;
        int t2 = 0;
#pragma unroll
        for (int i = 0; i < 8; i++)
#pragma unroll
            for (int j = i; j < 8; j++) {
                const float mm = S[8 + t2++];
                quad += (i == j ? 1.f : 2.f) * w[i] * w[j] * mm;
            }
        const float cnt = (float)NP;
        const float bb = sc_b[c];
        const float sum = lin + cnt * bb;
        const float ss = quad + 2.f * bb * lin + cnt * bb * bb;
        const float m = sum / cnt, v = ss / cnt - m * m;
        const float sc = sc_g[c] * rsqrtf(v + BN_EPS);
        scsc[c] = sc; scsh[c] = sc_bt[c] - m * sc;
    }
    if (tid < 16) {
        const int c = tid;
        const float cP = 1.f / (float)NP;
        float m = ws[WS_S_Y4 + c] * cP, v = ws[WS_SS_Y4 + c] * cP - m * m;
        float sc = p2_g[c] * rsqrtf(v + BN_EPS);
        p2sc[c] = sc; p2sh[c] = p2_bt[c] - m * sc;
    }
    __syncthreads();

    const int p = blockIdx.x * 256 + tid;
    const int b = p >> 16;
    const int n = p & (NN - 1);
    float x4[16];
#pragma unroll
    for (int c = 0; c < 16; c++) {
        float y = ws[WS_Y4 + c * NP + p] * p2sc[c] + p2sh[c];
        x4[c] = y > 0.f ? y : 0.f;
    }
    float f[8];
#pragma unroll
    for (int i = 0; i < 8; i++) f[i] = feats[(b * 8 + i) * NN + n];
#pragma unroll
    for (int c = 0; c < 32; c++) {
        float s = scbs[c];
#pragma unroll
        for (int i = 0; i < 8; i++) s += f[i] * scws[c * 8 + i];
        s = s * scsc[c] + scsh[c];  // bn, no activation
        float m = b2s[c];
#pragma unroll
        for (int o = 0; o < 16; o++) m += x4[o] * w2s[c * 16 + o];
        float v = m + s;
        out[(b * 32 + c) * NN + n] = v > 0.f ? v : 0.01f * v;  // LeakyReLU(0.01)
    }
}

extern "C" void kernel_launch(void* const* d_in, const int* in_sizes, int n_in,
                              void* d_out, int out_size, void* d_ws, size_t ws_size,
                              hipStream_t stream) {
    (void)in_sizes; (void)n_in; (void)out_size; (void)ws_size;
    const float* coords = (const float*)d_in[0];
    const float* features = (const float*)d_in[1];
    const int* idx = (const int*)d_in[2];
    const float* w1 = (const float*)d_in[3];
    const float* b1 = (const float*)d_in[4];
    const float* lse1_w = (const float*)d_in[5];
    const float* lse1_b = (const float*)d_in[6];
    const float* lse1_g = (const float*)d_in[7];
    const float* lse1_bt = (const float*)d_in[8];
    const float* p1_sw = (const float*)d_in[9];
    const float* p1_w = (const float*)d_in[10];
    const float* p1_b = (const float*)d_in[11];
    const float* p1_g = (const float*)d_in[12];
    const float* p1_bt = (const float*)d_in[13];
    const float* lse2_w = (const float*)d_in[14];
    const float* lse2_b = (const float*)d_in[15];
    const float* lse2_g = (const float*)d_in[16];
    const float* lse2_bt = (const float*)d_in[17];
    const float* p2_sw = (const float*)d_in[18];
    const float* p2_w = (const float*)d_in[19];
    const float* p2_b = (const float*)d_in[20];
    const float* p2_g = (const float*)d_in[21];
    const float* p2_bt = (const float*)d_in[22];
    const float* w2 = (const float*)d_in[23];
    const float* b2 = (const float*)d_in[24];
    const float* sc_w = (const float*)d_in[25];
    const float* sc_b = (const float*)d_in[26];
    const float* sc_g = (const float*)d_in[27];
    const float* sc_bt = (const float*)d_in[28];
    float* ws = (float*)d_ws;
    float* out = (float*)d_out;

    const int NBLK = NP / 256;
    hipMemsetAsync(ws, 0, 144 * sizeof(float), stream);
    k_stats<<<NBLK, 256, 0, stream>>>(coords, features, idx, ws);
    k_pool1<<<NBLK, 256, 0, stream>>>(coords, features, idx, w1, b1, lse1_w, lse1_b,
                                      lse1_g, lse1_bt, p1_sw, p1_w, p1_b, ws);
    k_pool2<<<NBLK, 256, 0, stream>>>(coords, idx, lse2_w, lse2_b, lse2_g, lse2_bt,
                                      p1_g, p1_bt, p2_sw, p2_w, p2_b, ws);
    k_final<<<NBLK, 256, 0, stream>>>(features, w2, b2, sc_w, sc_b, p2_g, p2_bt,
                                      sc_g, sc_bt, ws, out);
}